// Round 13
// baseline (261.290 us; speedup 1.0000x reference)
//
#include <hip/hip_runtime.h>
#include <hip/hip_bf16.h>
#include <stdint.h>

#define N_ROWS 262144
#define FEAT 1024
#define N_CORES 4096
#define HDIM 1024
#define BN_EPS 1e-5f

typedef __attribute__((ext_vector_type(8))) short bf16x8;
typedef __attribute__((ext_vector_type(8))) unsigned short u16x8;
typedef __attribute__((ext_vector_type(4))) float f32x4;

__device__ __forceinline__ unsigned short f2bf(float f) {
  __hip_bfloat16 h = __float2bfloat16(f);
  return __builtin_bit_cast(unsigned short, h);
}
__device__ __forceinline__ float bf2f(unsigned short u) {
  unsigned int x = ((unsigned int)u) << 16;
  return __builtin_bit_cast(float, x);
}

// async global->LDS, 16B per lane, dest = wave-uniform base + lane*16
__device__ __forceinline__ void gll16(const unsigned short* g, unsigned short* l) {
  __builtin_amdgcn_global_load_lds(
      (const __attribute__((address_space(1))) void*)g,
      (__attribute__((address_space(3))) void*)l, 16, 0, 0);
}

// --------------- PREP mega-kernel: segsum | weight transpose | stats zero
// R12 lesson: ~50us of the 61us non-segsum/non-GEMM residual is dispatch
// gaps. Fuse 3 independent prologue dispatches into one heterogeneous grid;
// transpose (~3us of work) hides inside segsum's 152us BW-bound phase.
// segsum path: 4-row unroll + nontemporal (measured 7.06 TB/s, R11/R12).
__global__ __launch_bounds__(256)
void k_prep(const float* __restrict__ x, const int* __restrict__ corelen,
            unsigned short* __restrict__ aggb,
            const float* __restrict__ W1, const float* __restrict__ W2,
            const float* __restrict__ W3, unsigned short* __restrict__ Wt,
            float* __restrict__ stats) {
  const int bid = blockIdx.x;
  const int t = threadIdx.x;
  if (bid < N_CORES) {
    // ---- segment sum
    const int seg = bid;
    const int start = corelen[seg];
    const int end = (seg + 1 < N_CORES) ? corelen[seg + 1] : N_ROWS;
    f32x4 a0 = {0.f, 0.f, 0.f, 0.f};
    f32x4 a1 = {0.f, 0.f, 0.f, 0.f};
    f32x4 a2 = {0.f, 0.f, 0.f, 0.f};
    f32x4 a3 = {0.f, 0.f, 0.f, 0.f};
    const f32x4* xp = (const f32x4*)(x + (size_t)start * FEAT) + t;
    int r = start;
    for (; r + 4 <= end; r += 4) {
      const f32x4 v0 = __builtin_nontemporal_load(xp);
      const f32x4 v1 = __builtin_nontemporal_load(xp + 256);
      const f32x4 v2 = __builtin_nontemporal_load(xp + 512);
      const f32x4 v3 = __builtin_nontemporal_load(xp + 768);
      a0 += v0; a1 += v1; a2 += v2; a3 += v3;
      xp += 4 * 256;
    }
    for (; r < end; ++r) {
      a0 += *xp;
      xp += 256;
    }
    a0 += a1; a2 += a3; a0 += a2;
    ushort4 o;
    o.x = f2bf(a0.x); o.y = f2bf(a0.y); o.z = f2bf(a0.z); o.w = f2bf(a0.w);
    *(ushort4*)(aggb + (size_t)seg * FEAT + t * 4) = o;
  } else if (bid < N_CORES + 3 * 1024) {
    // ---- W [K,N] f32 -> Wt [N,K] bf16 (32x32 tiles, 3 layers)
    __shared__ unsigned short tile[32][33];
    const int id = bid - N_CORES;
    const int l = id >> 10;           // layer 0..2
    const int q = id & 1023;
    const int n0 = (q & 31) * 32;
    const int k0 = (q >> 5) * 32;
    const float* W = (l == 0) ? W1 : (l == 1) ? W2 : W3;
    unsigned short* Wo = Wt + (size_t)l * HDIM * HDIM;
    const int tx = t & 31, ty = t >> 5;
#pragma unroll
    for (int i = 0; i < 4; ++i)
      tile[ty + 8 * i][tx] = f2bf(W[(size_t)(k0 + ty + 8 * i) * HDIM + n0 + tx]);
    __syncthreads();
#pragma unroll
    for (int i = 0; i < 4; ++i)
      Wo[(size_t)(n0 + ty + 8 * i) * HDIM + k0 + tx] = tile[tx][ty + 8 * i];
  } else {
    // ---- zero the 6*1024 f32 stats block
#pragma unroll
    for (int i = 0; i < 24; ++i) stats[t + i * 256] = 0.f;
  }
}

// ------------------------------------------------------------------ GEMM
// R13 experiment: BK=32 halves LDS (32->16KB) -> 10 single-wave blocks/CU
// = 2.5 waves/SIMD (was 1.25): double the latency-hiding TLP at identical
// MFMA:ds_read ratio. Same 2-deep counted-vmcnt prefetch (8 loads/tile,
// vmcnt(8)). Swizzle re-derived for 4-chunk rows: src col ^= (row&3)*8,
// read col ^= (fr&3)*8 -> bank-minimum (conflict-free) b128 reads.
#define BM 64
#define BN 64
#define BK 32
#define NT (HDIM / BK)
__global__ __launch_bounds__(64)
void k_gemm_bt(const unsigned short* __restrict__ A,
               const unsigned short* __restrict__ Bt,
               const float* __restrict__ bias,
               unsigned short* __restrict__ C,
               float* __restrict__ sums, float* __restrict__ sumsq) {
  __shared__ unsigned short As[2][BM * BK];
  __shared__ unsigned short Bs[2][BN * BK];
  const int lane = threadIdx.x;   // 0..63, one wave
  const int tileM = blockIdx.x * BM;
  const int tileN = blockIdx.y * BN;
  const int fr = lane & 15;
  const int kk = (lane >> 4) * 8;                 // k-chunk 0,8,16,24
  const int lr = lane >> 2;                       // staging row 0..15
  const int sc = ((lane & 3) * 8) ^ ((lr & 3) * 8);  // swizzled source k-col

  const unsigned short* pA = A + (size_t)(tileM + lr) * HDIM + sc;
  const unsigned short* pB = Bt + (size_t)(tileN + lr) * HDIM + sc;

  f32x4 acc[4][4] = {};

#define STAGE(buf, k0)                                                     \
  do {                                                                     \
    _Pragma("unroll") for (int j = 0; j < 4; ++j)                          \
        gll16(pA + (k0) + j * 16 * HDIM, &As[buf][(j * 16) * BK]);         \
    _Pragma("unroll") for (int j = 0; j < 4; ++j)                          \
        gll16(pB + (k0) + j * 16 * HDIM, &Bs[buf][(j * 16) * BK]);         \
  } while (0)

  STAGE(0, 0);
  STAGE(1, BK);
  for (int kt = 0; kt < NT; ++kt) {
    const int cur = kt & 1;
    if (kt < NT - 1)
      asm volatile("s_waitcnt vmcnt(8)" ::: "memory");
    else
      asm volatile("s_waitcnt vmcnt(0)" ::: "memory");
    __builtin_amdgcn_sched_barrier(0);
    const int pc = kk ^ ((fr & 3) * 8);           // swizzled read col
    bf16x8 af[4], bfv[4];
#pragma unroll
    for (int m = 0; m < 4; ++m)
      af[m] = *(const bf16x8*)&As[cur][(m * 16 + fr) * BK + pc];
#pragma unroll
    for (int n = 0; n < 4; ++n)
      bfv[n] = *(const bf16x8*)&Bs[cur][(n * 16 + fr) * BK + pc];
    asm volatile("s_waitcnt lgkmcnt(0)" ::: "memory");
    __builtin_amdgcn_sched_barrier(0);
    if (kt + 2 < NT) STAGE(cur, (kt + 2) * BK);
#pragma unroll
    for (int m = 0; m < 4; ++m)
#pragma unroll
      for (int n = 0; n < 4; ++n)
        acc[m][n] = __builtin_amdgcn_mfma_f32_16x16x32_bf16(
            af[m], bfv[n], acc[m][n], 0, 0, 0);
  }
#undef STAGE

  // epilogue: bias, store bf16 H, fused per-column partial BN stats (f32)
  const int cr = (lane >> 4) * 4;
  const int cc = lane & 15;
#pragma unroll
  for (int n = 0; n < 4; ++n) {
    const int col = tileN + n * 16 + cc;
    const float bv = bias[col];
    float s = 0.f, s2 = 0.f;
#pragma unroll
    for (int m = 0; m < 4; ++m) {
      unsigned short* cp = C + (size_t)(tileM + m * 16 + cr) * HDIM + col;
#pragma unroll
      for (int j = 0; j < 4; ++j) {
        const float h = acc[m][n][j] + bv;
        cp[(size_t)j * HDIM] = f2bf(h);
        s += h; s2 += h * h;
      }
    }
    s  += __shfl_xor(s, 16, 64);  s  += __shfl_xor(s, 32, 64);
    s2 += __shfl_xor(s2, 16, 64); s2 += __shfl_xor(s2, 32, 64);
    if ((lane >> 4) == 0) {
      atomicAdd(&sums[col], s);
      atomicAdd(&sumsq[col], s2);
    }
  }
}

// ------------------- normalize + ReLU, finalize fused (8 rsqrt/thread)
__global__ __launch_bounds__(256)
void k_norm_relu(const unsigned short* __restrict__ Hb,
                 const float* __restrict__ sums, const float* __restrict__ sumsq,
                 const float* __restrict__ g, const float* __restrict__ be,
                 unsigned short* __restrict__ Ab) {
  const size_t i8 = ((size_t)blockIdx.x * 256 + threadIdx.x) * 8;
  const u16x8 v = *(const u16x8*)(Hb + i8);
  const int c = (int)(i8 & (HDIM - 1));
  u16x8 o;
#pragma unroll
  for (int j = 0; j < 8; ++j) {
    const float mean = sums[c + j] * (1.f / N_CORES);
    const float var = sumsq[c + j] * (1.f / N_CORES) - mean * mean;
    const float sc = g[c + j] * rsqrtf(var + BN_EPS);
    const float sh = be[c + j] - mean * sc;
    o[j] = f2bf(fmaxf(bf2f(v[j]) * sc + sh, 0.f));
  }
  *(u16x8*)(Ab + i8) = o;
}

// -------- final layer: normalize+ReLU of Hb fused with [1024]x[1024,2] dot
__global__ __launch_bounds__(256)
void k_final(const unsigned short* __restrict__ Hb,
             const float* __restrict__ sums, const float* __restrict__ sumsq,
             const float* __restrict__ g, const float* __restrict__ be,
             const float* __restrict__ W4, const float* __restrict__ b4,
             float* __restrict__ out) {
  const int t = threadIdx.x;
  const int w = t >> 6, lane = t & 63;
  const int row = blockIdx.x * 4 + w;
  const int kbase = lane * 16;
  const unsigned short* a = Hb + (size_t)row * HDIM + kbase;
  float s0 = 0.f, s1 = 0.f;
#pragma unroll
  for (int j = 0; j < 16; ++j) {
    const int col = kbase + j;
    const float mean = sums[col] * (1.f / N_CORES);
    const float var = sumsq[col] * (1.f / N_CORES) - mean * mean;
    const float sc = g[col] * rsqrtf(var + BN_EPS);
    const float sh = be[col] - mean * sc;
    const float av = fmaxf(bf2f(a[j]) * sc + sh, 0.f);
    s0 += av * W4[col * 2 + 0];
    s1 += av * W4[col * 2 + 1];
  }
#pragma unroll
  for (int off = 32; off >= 1; off >>= 1) {
    s0 += __shfl_down(s0, off, 64);
    s1 += __shfl_down(s1, off, 64);
  }
  if (lane == 0) {
    out[row * 2 + 0] = s0 + b4[0];
    out[row * 2 + 1] = s1 + b4[1];
  }
}

extern "C" void kernel_launch(void* const* d_in, const int* in_sizes, int n_in,
                              void* d_out, int out_size, void* d_ws, size_t ws_size,
                              hipStream_t stream) {
  (void)in_sizes; (void)n_in; (void)out_size; (void)ws_size;
  const float* x       = (const float*)d_in[0];
  const int* corelen   = (const int*)d_in[1];
  const float* W1  = (const float*)d_in[2];
  const float* b1  = (const float*)d_in[3];
  const float* g1  = (const float*)d_in[4];
  const float* be1 = (const float*)d_in[5];
  const float* W2  = (const float*)d_in[6];
  const float* b2  = (const float*)d_in[7];
  const float* g2  = (const float*)d_in[8];
  const float* be2 = (const float*)d_in[9];
  const float* W3  = (const float*)d_in[10];
  const float* b3  = (const float*)d_in[11];
  const float* g3  = (const float*)d_in[12];
  const float* be3 = (const float*)d_in[13];
  const float* W4  = (const float*)d_in[14];
  const float* b4  = (const float*)d_in[15];
  float* out = (float*)d_out;

  char* ws = (char*)d_ws;
  unsigned short* Hb   = (unsigned short*)(ws);               //  8 MB [4096,1024] bf16 (pre-BN)
  unsigned short* Abf  = (unsigned short*)(ws + (8u << 20));  //  8 MB [4096,1024] bf16 (activations)
  unsigned short* Wt   = (unsigned short*)(ws + (16u << 20)); //  6 MB 3x[1024,1024] bf16
  float* stats = (float*)(ws + (22u << 20));                  // 6*1024 f32 (per-layer sums/sumsq)

  // one fused prologue dispatch: segsum + 3 transposes + stats zero
  k_prep<<<N_CORES + 3 * 1024 + 1, 256, 0, stream>>>(
      x, corelen, Abf, W1, W2, W3, Wt, stats);

  const float* bs[3]  = {b1, b2, b3};
  const float* gs[3]  = {g1, g2, g3};
  const float* bes[3] = {be1, be2, be3};
  for (int l = 0; l < 3; ++l) {
    float* sums  = stats + l * 2 * HDIM;
    float* sumsq = sums + HDIM;
    k_gemm_bt<<<dim3(N_CORES / BM, HDIM / BN), 64, 0, stream>>>(
        Abf, Wt + (size_t)l * HDIM * HDIM, bs[l], Hb, sums, sumsq);
    if (l < 2)
      k_norm_relu<<<(N_CORES * HDIM / 8) / 256, 256, 0, stream>>>(
          Hb, sums, sumsq, gs[l], bes[l], Abf);
    else
      k_final<<<N_CORES / 4, 256, 0, stream>>>(
          Hb, sums, sumsq, gs[l], bes[l], W4, b4, out);
  }
}

// Round 14
// 249.788 us; speedup vs baseline: 1.0460x; 1.0460x over previous
//
#include <hip/hip_runtime.h>
#include <hip/hip_bf16.h>
#include <stdint.h>

#define N_ROWS 262144
#define FEAT 1024
#define N_CORES 4096
#define HDIM 1024
#define BN_EPS 1e-5f

typedef __attribute__((ext_vector_type(8))) short bf16x8;
typedef __attribute__((ext_vector_type(8))) unsigned short u16x8;
typedef __attribute__((ext_vector_type(4))) float f32x4;

__device__ __forceinline__ unsigned short f2bf(float f) {
  __hip_bfloat16 h = __float2bfloat16(f);
  return __builtin_bit_cast(unsigned short, h);
}
__device__ __forceinline__ float bf2f(unsigned short u) {
  unsigned int x = ((unsigned int)u) << 16;
  return __builtin_bit_cast(float, x);
}

// async global->LDS, 16B per lane, dest = wave-uniform base + lane*16
__device__ __forceinline__ void gll16(const unsigned short* g, unsigned short* l) {
  __builtin_amdgcn_global_load_lds(
      (const __attribute__((address_space(1))) void*)g,
      (__attribute__((address_space(3))) void*)l, 16, 0, 0);
}

// --------------- PREP mega-kernel: segsum | weight transpose | stats zero
// (kept from R13 -- fusion of 3 prologue dispatches; transpose hides inside
// segsum's BW-bound phase). segsum: 4-row unroll + nontemporal, 7.06 TB/s.
__global__ __launch_bounds__(256)
void k_prep(const float* __restrict__ x, const int* __restrict__ corelen,
            unsigned short* __restrict__ aggb,
            const float* __restrict__ W1, const float* __restrict__ W2,
            const float* __restrict__ W3, unsigned short* __restrict__ Wt,
            float* __restrict__ stats) {
  const int bid = blockIdx.x;
  const int t = threadIdx.x;
  if (bid < N_CORES) {
    const int seg = bid;
    const int start = corelen[seg];
    const int end = (seg + 1 < N_CORES) ? corelen[seg + 1] : N_ROWS;
    f32x4 a0 = {0.f, 0.f, 0.f, 0.f};
    f32x4 a1 = {0.f, 0.f, 0.f, 0.f};
    f32x4 a2 = {0.f, 0.f, 0.f, 0.f};
    f32x4 a3 = {0.f, 0.f, 0.f, 0.f};
    const f32x4* xp = (const f32x4*)(x + (size_t)start * FEAT) + t;
    int r = start;
    for (; r + 4 <= end; r += 4) {
      const f32x4 v0 = __builtin_nontemporal_load(xp);
      const f32x4 v1 = __builtin_nontemporal_load(xp + 256);
      const f32x4 v2 = __builtin_nontemporal_load(xp + 512);
      const f32x4 v3 = __builtin_nontemporal_load(xp + 768);
      a0 += v0; a1 += v1; a2 += v2; a3 += v3;
      xp += 4 * 256;
    }
    for (; r < end; ++r) {
      a0 += *xp;
      xp += 256;
    }
    a0 += a1; a2 += a3; a0 += a2;
    ushort4 o;
    o.x = f2bf(a0.x); o.y = f2bf(a0.y); o.z = f2bf(a0.z); o.w = f2bf(a0.w);
    *(ushort4*)(aggb + (size_t)seg * FEAT + t * 4) = o;
  } else if (bid < N_CORES + 3 * 1024) {
    __shared__ unsigned short tile[32][33];
    const int id = bid - N_CORES;
    const int l = id >> 10;           // layer 0..2
    const int q = id & 1023;
    const int n0 = (q & 31) * 32;
    const int k0 = (q >> 5) * 32;
    const float* W = (l == 0) ? W1 : (l == 1) ? W2 : W3;
    unsigned short* Wo = Wt + (size_t)l * HDIM * HDIM;
    const int tx = t & 31, ty = t >> 5;
#pragma unroll
    for (int i = 0; i < 4; ++i)
      tile[ty + 8 * i][tx] = f2bf(W[(size_t)(k0 + ty + 8 * i) * HDIM + n0 + tx]);
    __syncthreads();
#pragma unroll
    for (int i = 0; i < 4; ++i)
      Wo[(size_t)(n0 + ty + 8 * i) * HDIM + k0 + tx] = tile[tx][ty + 8 * i];
  } else {
#pragma unroll
    for (int i = 0; i < 24; ++i) stats[t + i * 256] = 0.f;
  }
}

// ------------------------------------------------------------------ GEMM
// REVERTED to R8/R12's verified BK=64 single-wave kernel (14.6 us/dispatch
// measured, R9). R13 lesson: grid=1024 caps residency at 4 blocks/CU, so
// BK=32's LDS saving bought no TLP and halved prefetch flight time (+10us).
#define BM 64
#define BN 64
#define BK 64
#define NT (HDIM / BK)
__global__ __launch_bounds__(64)
void k_gemm_bt(const unsigned short* __restrict__ A,
               const unsigned short* __restrict__ Bt,
               const float* __restrict__ bias,
               unsigned short* __restrict__ C,
               float* __restrict__ sums, float* __restrict__ sumsq) {
  __shared__ unsigned short As[2][BM * BK];
  __shared__ unsigned short Bs[2][BN * BK];
  const int lane = threadIdx.x;   // 0..63, one wave
  const int tileM = blockIdx.x * BM;
  const int tileN = blockIdx.y * BN;
  const int fr = lane & 15;
  const int kk = (lane >> 4) * 8;
  const int lr = lane >> 3;                       // 0..7
  const int sc = ((lane & 7) * 8) ^ (lr << 3);    // swizzled source k-col

  const unsigned short* pA = A + (size_t)(tileM + lr) * HDIM + sc;
  const unsigned short* pB = Bt + (size_t)(tileN + lr) * HDIM + sc;

  f32x4 acc[4][4] = {};

#define STAGE(buf, k0)                                                     \
  do {                                                                     \
    _Pragma("unroll") for (int j = 0; j < 8; ++j)                          \
        gll16(pA + (k0) + j * 8 * HDIM, &As[buf][(j * 8) * BK]);           \
    _Pragma("unroll") for (int j = 0; j < 8; ++j)                          \
        gll16(pB + (k0) + j * 8 * HDIM, &Bs[buf][(j * 8) * BK]);           \
  } while (0)

  STAGE(0, 0);
  STAGE(1, BK);
  for (int kt = 0; kt < NT; ++kt) {
    const int cur = kt & 1;
    if (kt < NT - 1)
      asm volatile("s_waitcnt vmcnt(16)" ::: "memory");
    else
      asm volatile("s_waitcnt vmcnt(0)" ::: "memory");
    __builtin_amdgcn_sched_barrier(0);
    bf16x8 af[2][4], bfv[2][4];
#pragma unroll
    for (int ks = 0; ks < 2; ++ks) {
      const int pc = (ks * 32 + kk) ^ ((fr & 7) << 3);  // swizzled read col
#pragma unroll
      for (int m = 0; m < 4; ++m)
        af[ks][m] = *(const bf16x8*)&As[cur][(m * 16 + fr) * BK + pc];
#pragma unroll
      for (int n = 0; n < 4; ++n)
        bfv[ks][n] = *(const bf16x8*)&Bs[cur][(n * 16 + fr) * BK + pc];
    }
    asm volatile("s_waitcnt lgkmcnt(0)" ::: "memory");
    __builtin_amdgcn_sched_barrier(0);
    if (kt + 2 < NT) STAGE(cur, (kt + 2) * BK);
#pragma unroll
    for (int ks = 0; ks < 2; ++ks)
#pragma unroll
      for (int m = 0; m < 4; ++m)
#pragma unroll
        for (int n = 0; n < 4; ++n)
          acc[m][n] = __builtin_amdgcn_mfma_f32_16x16x32_bf16(
              af[ks][m], bfv[ks][n], acc[m][n], 0, 0, 0);
  }
#undef STAGE

  // epilogue: bias, store bf16 H, fused per-column partial BN stats (f32)
  const int cr = (lane >> 4) * 4;
  const int cc = lane & 15;
#pragma unroll
  for (int n = 0; n < 4; ++n) {
    const int col = tileN + n * 16 + cc;
    const float bv = bias[col];
    float s = 0.f, s2 = 0.f;
#pragma unroll
    for (int m = 0; m < 4; ++m) {
      unsigned short* cp = C + (size_t)(tileM + m * 16 + cr) * HDIM + col;
#pragma unroll
      for (int j = 0; j < 4; ++j) {
        const float h = acc[m][n][j] + bv;
        cp[(size_t)j * HDIM] = f2bf(h);
        s += h; s2 += h * h;
      }
    }
    s  += __shfl_xor(s, 16, 64);  s  += __shfl_xor(s, 32, 64);
    s2 += __shfl_xor(s2, 16, 64); s2 += __shfl_xor(s2, 32, 64);
    if ((lane >> 4) == 0) {
      atomicAdd(&sums[col], s);
      atomicAdd(&sumsq[col], s2);
    }
  }
}

// ------------------- normalize + ReLU, finalize fused (8 rsqrt/thread)
__global__ __launch_bounds__(256)
void k_norm_relu(const unsigned short* __restrict__ Hb,
                 const float* __restrict__ sums, const float* __restrict__ sumsq,
                 const float* __restrict__ g, const float* __restrict__ be,
                 unsigned short* __restrict__ Ab) {
  const size_t i8 = ((size_t)blockIdx.x * 256 + threadIdx.x) * 8;
  const u16x8 v = *(const u16x8*)(Hb + i8);
  const int c = (int)(i8 & (HDIM - 1));
  u16x8 o;
#pragma unroll
  for (int j = 0; j < 8; ++j) {
    const float mean = sums[c + j] * (1.f / N_CORES);
    const float var = sumsq[c + j] * (1.f / N_CORES) - mean * mean;
    const float sc = g[c + j] * rsqrtf(var + BN_EPS);
    const float sh = be[c + j] - mean * sc;
    o[j] = f2bf(fmaxf(bf2f(v[j]) * sc + sh, 0.f));
  }
  *(u16x8*)(Ab + i8) = o;
}

// -------- final layer: normalize+ReLU of Hb fused with [1024]x[1024,2] dot
__global__ __launch_bounds__(256)
void k_final(const unsigned short* __restrict__ Hb,
             const float* __restrict__ sums, const float* __restrict__ sumsq,
             const float* __restrict__ g, const float* __restrict__ be,
             const float* __restrict__ W4, const float* __restrict__ b4,
             float* __restrict__ out) {
  const int t = threadIdx.x;
  const int w = t >> 6, lane = t & 63;
  const int row = blockIdx.x * 4 + w;
  const int kbase = lane * 16;
  const unsigned short* a = Hb + (size_t)row * HDIM + kbase;
  float s0 = 0.f, s1 = 0.f;
#pragma unroll
  for (int j = 0; j < 16; ++j) {
    const int col = kbase + j;
    const float mean = sums[col] * (1.f / N_CORES);
    const float var = sumsq[col] * (1.f / N_CORES) - mean * mean;
    const float sc = g[col] * rsqrtf(var + BN_EPS);
    const float sh = be[col] - mean * sc;
    const float av = fmaxf(bf2f(a[j]) * sc + sh, 0.f);
    s0 += av * W4[col * 2 + 0];
    s1 += av * W4[col * 2 + 1];
  }
#pragma unroll
  for (int off = 32; off >= 1; off >>= 1) {
    s0 += __shfl_down(s0, off, 64);
    s1 += __shfl_down(s1, off, 64);
  }
  if (lane == 0) {
    out[row * 2 + 0] = s0 + b4[0];
    out[row * 2 + 1] = s1 + b4[1];
  }
}

extern "C" void kernel_launch(void* const* d_in, const int* in_sizes, int n_in,
                              void* d_out, int out_size, void* d_ws, size_t ws_size,
                              hipStream_t stream) {
  (void)in_sizes; (void)n_in; (void)out_size; (void)ws_size;
  const float* x       = (const float*)d_in[0];
  const int* corelen   = (const int*)d_in[1];
  const float* W1  = (const float*)d_in[2];
  const float* b1  = (const float*)d_in[3];
  const float* g1  = (const float*)d_in[4];
  const float* be1 = (const float*)d_in[5];
  const float* W2  = (const float*)d_in[6];
  const float* b2  = (const float*)d_in[7];
  const float* g2  = (const float*)d_in[8];
  const float* be2 = (const float*)d_in[9];
  const float* W3  = (const float*)d_in[10];
  const float* b3  = (const float*)d_in[11];
  const float* g3  = (const float*)d_in[12];
  const float* be3 = (const float*)d_in[13];
  const float* W4  = (const float*)d_in[14];
  const float* b4  = (const float*)d_in[15];
  float* out = (float*)d_out;

  char* ws = (char*)d_ws;
  unsigned short* Hb   = (unsigned short*)(ws);               //  8 MB [4096,1024] bf16 (pre-BN)
  unsigned short* Abf  = (unsigned short*)(ws + (8u << 20));  //  8 MB [4096,1024] bf16 (activations)
  unsigned short* Wt   = (unsigned short*)(ws + (16u << 20)); //  6 MB 3x[1024,1024] bf16
  float* stats = (float*)(ws + (22u << 20));                  // 6*1024 f32 (per-layer sums/sumsq)

  // one fused prologue dispatch: segsum + 3 transposes + stats zero
  k_prep<<<N_CORES + 3 * 1024 + 1, 256, 0, stream>>>(
      x, corelen, Abf, W1, W2, W3, Wt, stats);

  const float* bs[3]  = {b1, b2, b3};
  const float* gs[3]  = {g1, g2, g3};
  const float* bes[3] = {be1, be2, be3};
  for (int l = 0; l < 3; ++l) {
    float* sums  = stats + l * 2 * HDIM;
    float* sumsq = sums + HDIM;
    k_gemm_bt<<<dim3(N_CORES / BM, HDIM / BN), 64, 0, stream>>>(
        Abf, Wt + (size_t)l * HDIM * HDIM, bs[l], Hb, sums, sumsq);
    if (l < 2)
      k_norm_relu<<<(N_CORES * HDIM / 8) / 256, 256, 0, stream>>>(
          Hb, sums, sumsq, gs[l], bes[l], Abf);
    else
      k_final<<<N_CORES / 4, 256, 0, stream>>>(
          Hb, sums, sumsq, gs[l], bes[l], W4, b4, out);
  }
}